// Round 1
// baseline (224.886 us; speedup 1.0000x reference)
//
#include <hip/hip_runtime.h>
#include <hip/hip_bf16.h>

#define N_NODES 50000
#define HD 128
#define NTILES (N_NODES / 16)   // 3125, exact

using short8  = __attribute__((ext_vector_type(8))) short;   // 8 x bf16 bits
using floatx4 = __attribute__((ext_vector_type(4))) float;

__device__ __forceinline__ short f2bf(float f) {
  union { float fp; unsigned u; } un; un.fp = f;
  unsigned u = un.u + 0x7fffu + ((un.u >> 16) & 1u);   // RNE
  return (short)(u >> 16);
}

// ---- init: deg=1 (self-loop), s=0, vacc=0 ----
__global__ void k_init(int* __restrict__ deg, float* __restrict__ s,
                       float* __restrict__ vacc) {
  int i = blockIdx.x * 256 + threadIdx.x;
  if (i < N_NODES) { deg[i] = 1; s[i] = 0.f; }
  if (i < 2 * HD) vacc[i] = 0.f;
}

// ---- in-degree histogram over dst ----
__global__ void k_deg(const int* __restrict__ dst, int* __restrict__ deg, int E) {
  int i = blockIdx.x * 256 + threadIdx.x;
  if (i < E) atomicAdd(&deg[dst[i]], 1);
}

// ---- s[src] += rsqrt(deg[dst]) ----
__global__ void k_s(const int* __restrict__ src, const int* __restrict__ dst,
                    const int* __restrict__ deg, float* __restrict__ s, int E) {
  int i = blockIdx.x * 256 + threadIdx.x;
  if (i < E) {
    float dv = rsqrtf((float)deg[dst[i]]);
    atomicAdd(&s[src[i]], dv);
  }
}

// ---- w[n] = dinv[n]*(s[n] + dinv[n])   (in-place into s) ----
__global__ void k_w(const int* __restrict__ deg, float* __restrict__ s) {
  int i = blockIdx.x * 256 + threadIdx.x;
  if (i < N_NODES) {
    float dv = rsqrtf((float)deg[i]);
    s[i] = dv * (s[i] + dv);
  }
}

// ---- main: v[b,h] = sum_n w[n] * relu(x[b,n,:] @ W_feat + b_feat)[h] ----
__global__ __launch_bounds__(256, 2) void k_main(
    const float* __restrict__ x, const float* __restrict__ Wf,
    const float* __restrict__ bfeat, const float* __restrict__ w,
    float* __restrict__ vacc) {
  // B-fragments of W_feat, pre-swizzled: frag (kt,t), lane-contiguous 16B
  __shared__ __align__(16) short lW[32 * 64 * 8];   // 32 KB
  const int tid = threadIdx.x;
  for (int c = tid; c < 2048; c += 256) {           // c = (kt*8+t)*64 + lane
    int lane = c & 63, t = (c >> 6) & 7, kt = c >> 9;
    int h = t * 16 + (lane & 15);
    int dbase = kt * 32 + (lane >> 4) * 8;
    short8 v;
#pragma unroll
    for (int j = 0; j < 8; ++j) v[j] = f2bf(Wf[(dbase + j) * HD + h]);
    *(short8*)&lW[c * 8] = v;
  }
  __syncthreads();

  const int lane = tid & 63;
  const int wave = tid >> 6;
  const int col  = lane & 15;
  const int quad = lane >> 4;
  const int b    = blockIdx.y;

  float bias[8];
#pragma unroll
  for (int t = 0; t < 8; ++t) bias[t] = bfeat[t * 16 + col];

  float pv[8];
#pragma unroll
  for (int t = 0; t < 8; ++t) pv[t] = 0.f;

  const float* xb = x + (size_t)b * N_NODES * HD;
  for (int tile = blockIdx.x * 4 + wave; tile < NTILES; tile += gridDim.x * 4) {
    const int n0 = tile * 16;
    const float* xr = xb + (size_t)(n0 + col) * HD + quad * 8;  // A row = col
    floatx4 acc[8] = {};
#pragma unroll
    for (int kt = 0; kt < 4; ++kt) {
      floatx4 xlo = *(const floatx4*)(xr + kt * 32);
      floatx4 xhi = *(const floatx4*)(xr + kt * 32 + 4);
      short8 a;
#pragma unroll
      for (int j = 0; j < 4; ++j) { a[j] = f2bf(xlo[j]); a[j + 4] = f2bf(xhi[j]); }
#pragma unroll
      for (int t = 0; t < 8; ++t) {
        short8 bf = *(const short8*)&lW[((kt * 8 + t) * 64 + lane) * 8];
        acc[t] = __builtin_amdgcn_mfma_f32_16x16x32_bf16(a, bf, acc[t], 0, 0, 0);
      }
    }
    floatx4 w4 = *(const floatx4*)&w[n0 + quad * 4];  // D rows = quad*4 + r
#pragma unroll
    for (int t = 0; t < 8; ++t) {
#pragma unroll
      for (int r = 0; r < 4; ++r) {
        float y = acc[t][r] + bias[t];
        pv[t] += fmaxf(y, 0.f) * w4[r];
      }
    }
  }
#pragma unroll
  for (int t = 0; t < 8; ++t) {
    float v = pv[t];
    v += __shfl_xor(v, 32, 64);
    v += __shfl_xor(v, 16, 64);
    if (quad == 0) atomicAdd(&vacc[b * HD + t * 16 + col], v);
  }
}

// ---- tiny head: pooled = (v/N)@W_gcn + b_gcn; z = relu(pooled@W_fc1+b1); out = z@W_fc2+b2
__global__ void k_final(const float* __restrict__ vacc, const float* __restrict__ Wg,
                        const float* __restrict__ bg, const float* __restrict__ W1,
                        const float* __restrict__ b1, const float* __restrict__ W2,
                        const float* __restrict__ b2, float* __restrict__ out) {
  __shared__ float pooled[2][HD];
  __shared__ float z[2][HD];
  __shared__ float red[256];
  const int tid = threadIdx.x;
  const int b = tid >> 7, h = tid & 127;
  float acc = 0.f;
  for (int k = 0; k < HD; ++k) acc += vacc[b * HD + k] * Wg[k * HD + h];
  pooled[b][h] = acc * (1.0f / N_NODES) + bg[h];
  __syncthreads();
  acc = 0.f;
  for (int k = 0; k < HD; ++k) acc += pooled[b][k] * W1[k * HD + h];
  z[b][h] = fmaxf(acc + b1[h], 0.f);
  __syncthreads();
  red[tid] = z[b][h] * W2[h];
  __syncthreads();
  if (tid < 2) {
    float sum = 0.f;
    for (int k = 0; k < HD; ++k) sum += red[tid * HD + k];
    out[tid] = sum + b2[0];
  }
}

extern "C" void kernel_launch(void* const* d_in, const int* in_sizes, int n_in,
                              void* d_out, int out_size, void* d_ws, size_t ws_size,
                              hipStream_t stream) {
  const float* x  = (const float*)d_in[0];
  const int*   ei = (const int*)d_in[1];
  const float* Wf = (const float*)d_in[2];
  const float* bf = (const float*)d_in[3];
  const float* Wg = (const float*)d_in[4];
  const float* bg = (const float*)d_in[5];
  const float* W1 = (const float*)d_in[6];
  const float* b1 = (const float*)d_in[7];
  const float* W2 = (const float*)d_in[8];
  const float* b2 = (const float*)d_in[9];
  float* out = (float*)d_out;

  const int E = in_sizes[1] / 2;
  const int* src = ei;
  const int* dst = ei + E;

  char* ws = (char*)d_ws;
  const size_t stride = (N_NODES * 4 + 255) & ~(size_t)255;  // 200192 B
  int*   deg  = (int*)ws;
  float* s    = (float*)(ws + stride);       // becomes w[] after k_w
  float* vacc = (float*)(ws + 2 * stride);

  k_init<<<(N_NODES + 255) / 256, 256, 0, stream>>>(deg, s, vacc);
  k_deg<<<(E + 255) / 256, 256, 0, stream>>>(dst, deg, E);
  k_s<<<(E + 255) / 256, 256, 0, stream>>>(src, dst, deg, s, E);
  k_w<<<(N_NODES + 255) / 256, 256, 0, stream>>>(deg, s);
  dim3 grid(256, 2);
  k_main<<<grid, 256, 0, stream>>>(x, Wf, bf, s, vacc);
  k_final<<<1, 256, 0, stream>>>(vacc, Wg, bg, W1, b1, W2, b2, out);
  (void)n_in; (void)out_size; (void)ws_size;
}

// Round 2
// 152.516 us; speedup vs baseline: 1.4745x; 1.4745x over previous
//
#include <hip/hip_runtime.h>
#include <hip/hip_bf16.h>

#define N_NODES 50000
#define HD 128
#define NTILES (N_NODES / 16)   // 3125, exact
#define NSLICE 64               // edge slices for privatized scatter
#define NQUART 12500            // nodes per LDS quarter (50 KB f32 bins)

using short8  = __attribute__((ext_vector_type(8))) short;   // 8 x bf16 bits
using floatx4 = __attribute__((ext_vector_type(4))) float;

__device__ __forceinline__ short f2bf(float f) {
  union { float fp; unsigned u; } un; un.fp = f;
  unsigned u = un.u + 0x7fffu + ((un.u >> 16) & 1u);   // RNE
  return (short)(u >> 16);
}

// =======================  fast edge phase (no device atomics)  ==============
// partial[s][n] accumulates per-slice sums; block (slice, quarter) owns
// 12500-node LDS bins and writes them back non-atomically.
template <bool GATHER>
__global__ __launch_bounds__(1024) void k_scatter(
    const int* __restrict__ keys, const int* __restrict__ other,
    const float* __restrict__ dinv, float* __restrict__ partial,
    int E, int perSlice) {
  __shared__ __align__(16) float bins[NQUART];
  const int tid = threadIdx.x;
  for (int i = tid; i < NQUART / 4; i += 1024)
    ((float4*)bins)[i] = make_float4(0.f, 0.f, 0.f, 0.f);
  __syncthreads();

  const int slice = blockIdx.x;
  const int base  = blockIdx.y * NQUART;
  const int e0 = slice * perSlice;
  const int e1 = min(e0 + perSlice, E);
  for (int e = e0 + tid; e < e1; e += 1024) {
    int k = keys[e];
    if ((unsigned)(k - base) < (unsigned)NQUART) {
      float v = GATHER ? dinv[other[e]] : 1.0f;
      atomicAdd(&bins[k - base], v);           // ds_add_f32, LDS-local
    }
  }
  __syncthreads();

  float* out = partial + (size_t)slice * N_NODES + base;
  for (int i = tid; i < NQUART / 4; i += 1024)
    ((float4*)out)[i] = ((const float4*)bins)[i];
}

// dinv[n] = rsqrt(1 + sum_s partial[s][n])      (self-loop -> +1)
__global__ void k_merge_deg(const float* __restrict__ partial,
                            float* __restrict__ dinv) {
  int n = blockIdx.x * 256 + threadIdx.x;
  if (n >= N_NODES) return;
  float s = 1.0f;
  for (int sl = 0; sl < NSLICE; ++sl) s += partial[(size_t)sl * N_NODES + n];
  dinv[n] = rsqrtf(s);
}

// w[n] = dinv[n] * (sum_s partial[s][n] + dinv[n]);  also zero vacc
__global__ void k_merge_w(const float* __restrict__ partial,
                          const float* __restrict__ dinv,
                          float* __restrict__ w, float* __restrict__ vacc) {
  int n = blockIdx.x * 256 + threadIdx.x;
  if (n < 2 * HD) vacc[n] = 0.f;
  if (n >= N_NODES) return;
  float s = 0.0f;
  for (int sl = 0; sl < NSLICE; ++sl) s += partial[(size_t)sl * N_NODES + n];
  float dv = dinv[n];
  w[n] = dv * (s + dv);
}

// =======================  fallback edge phase (device atomics)  =============
__global__ void k_init(int* __restrict__ deg, float* __restrict__ s,
                       float* __restrict__ vacc) {
  int i = blockIdx.x * 256 + threadIdx.x;
  if (i < N_NODES) { deg[i] = 1; s[i] = 0.f; }
  if (i < 2 * HD) vacc[i] = 0.f;
}
__global__ void k_deg_at(const int* __restrict__ dst, int* __restrict__ deg, int E) {
  int i = blockIdx.x * 256 + threadIdx.x;
  if (i < E) atomicAdd(&deg[dst[i]], 1);
}
__global__ void k_s_at(const int* __restrict__ src, const int* __restrict__ dst,
                       const int* __restrict__ deg, float* __restrict__ s, int E) {
  int i = blockIdx.x * 256 + threadIdx.x;
  if (i < E) {
    float dv = rsqrtf((float)deg[dst[i]]);
    atomicAdd(&s[src[i]], dv);
  }
}
__global__ void k_w_at(const int* __restrict__ deg, float* __restrict__ s) {
  int i = blockIdx.x * 256 + threadIdx.x;
  if (i < N_NODES) {
    float dv = rsqrtf((float)deg[i]);
    s[i] = dv * (s[i] + dv);
  }
}

// ---- main: vacc[b,h] = sum_n w[n] * relu(x[b,n,:] @ W_feat + b_feat)[h] ----
__global__ __launch_bounds__(256, 2) void k_main(
    const float* __restrict__ x, const float* __restrict__ Wf,
    const float* __restrict__ bfeat, const float* __restrict__ w,
    float* __restrict__ vacc) {
  // B-fragments of W_feat, pre-swizzled: frag (kt,t), lane-contiguous 16B
  __shared__ __align__(16) short lW[32 * 64 * 8];   // 32 KB
  const int tid = threadIdx.x;
  for (int c = tid; c < 2048; c += 256) {           // c = (kt*8+t)*64 + lane
    int lane = c & 63, t = (c >> 6) & 7, kt = c >> 9;
    int h = t * 16 + (lane & 15);
    int dbase = kt * 32 + (lane >> 4) * 8;
    short8 v;
#pragma unroll
    for (int j = 0; j < 8; ++j) v[j] = f2bf(Wf[(dbase + j) * HD + h]);
    *(short8*)&lW[c * 8] = v;
  }
  __syncthreads();

  const int lane = tid & 63;
  const int wave = tid >> 6;
  const int col  = lane & 15;
  const int quad = lane >> 4;
  const int b    = blockIdx.y;

  float bias[8];
#pragma unroll
  for (int t = 0; t < 8; ++t) bias[t] = bfeat[t * 16 + col];

  float pv[8];
#pragma unroll
  for (int t = 0; t < 8; ++t) pv[t] = 0.f;

  const float* xb = x + (size_t)b * N_NODES * HD;
  for (int tile = blockIdx.x * 4 + wave; tile < NTILES; tile += gridDim.x * 4) {
    const int n0 = tile * 16;
    const float* xr = xb + (size_t)(n0 + col) * HD + quad * 8;  // A row = col
    floatx4 acc[8] = {};
#pragma unroll
    for (int kt = 0; kt < 4; ++kt) {
      floatx4 xlo = *(const floatx4*)(xr + kt * 32);
      floatx4 xhi = *(const floatx4*)(xr + kt * 32 + 4);
      short8 a;
#pragma unroll
      for (int j = 0; j < 4; ++j) { a[j] = f2bf(xlo[j]); a[j + 4] = f2bf(xhi[j]); }
#pragma unroll
      for (int t = 0; t < 8; ++t) {
        short8 bf = *(const short8*)&lW[((kt * 8 + t) * 64 + lane) * 8];
        acc[t] = __builtin_amdgcn_mfma_f32_16x16x32_bf16(a, bf, acc[t], 0, 0, 0);
      }
    }
    floatx4 w4 = *(const floatx4*)&w[n0 + quad * 4];  // D rows = quad*4 + r
#pragma unroll
    for (int t = 0; t < 8; ++t) {
#pragma unroll
      for (int r = 0; r < 4; ++r) {
        float y = acc[t][r] + bias[t];
        pv[t] += fmaxf(y, 0.f) * w4[r];
      }
    }
  }

  // cross-wave LDS reduce, then ONE atomic per (b,h) per block (32k total)
  __syncthreads();                     // all lW reads done; reuse as scratch
  float* red = (float*)lW;             // need 4*128 floats
#pragma unroll
  for (int t = 0; t < 8; ++t) {
    float v = pv[t];
    v += __shfl_xor(v, 32, 64);
    v += __shfl_xor(v, 16, 64);
    if (quad == 0) red[wave * 128 + t * 16 + col] = v;
  }
  __syncthreads();
  if (tid < 128) {
    float v = red[tid] + red[128 + tid] + red[256 + tid] + red[384 + tid];
    atomicAdd(&vacc[b * HD + tid], v);
  }
}

// ---- tiny head ----
__global__ void k_final(const float* __restrict__ vacc, const float* __restrict__ Wg,
                        const float* __restrict__ bg, const float* __restrict__ W1,
                        const float* __restrict__ b1, const float* __restrict__ W2,
                        const float* __restrict__ b2, float* __restrict__ out) {
  __shared__ float pooled[2][HD];
  __shared__ float z[2][HD];
  __shared__ float red[256];
  const int tid = threadIdx.x;
  const int b = tid >> 7, h = tid & 127;
  float acc = 0.f;
  for (int k = 0; k < HD; ++k) acc += vacc[b * HD + k] * Wg[k * HD + h];
  pooled[b][h] = acc * (1.0f / N_NODES) + bg[h];
  __syncthreads();
  acc = 0.f;
  for (int k = 0; k < HD; ++k) acc += pooled[b][k] * W1[k * HD + h];
  z[b][h] = fmaxf(acc + b1[h], 0.f);
  __syncthreads();
  red[tid] = z[b][h] * W2[h];
  __syncthreads();
  if (tid < 2) {
    float sum = 0.f;
    for (int k = 0; k < HD; ++k) sum += red[tid * HD + k];
    out[tid] = sum + b2[0];
  }
}

extern "C" void kernel_launch(void* const* d_in, const int* in_sizes, int n_in,
                              void* d_out, int out_size, void* d_ws, size_t ws_size,
                              hipStream_t stream) {
  const float* x  = (const float*)d_in[0];
  const int*   ei = (const int*)d_in[1];
  const float* Wf = (const float*)d_in[2];
  const float* bf = (const float*)d_in[3];
  const float* Wg = (const float*)d_in[4];
  const float* bg = (const float*)d_in[5];
  const float* W1 = (const float*)d_in[6];
  const float* b1 = (const float*)d_in[7];
  const float* W2 = (const float*)d_in[8];
  const float* b2 = (const float*)d_in[9];
  float* out = (float*)d_out;

  const int E = in_sizes[1] / 2;
  const int* src = ei;
  const int* dst = ei + E;
  const int perSlice = (E + NSLICE - 1) / NSLICE;

  char* ws = (char*)d_ws;
  const size_t partialB = (size_t)NSLICE * N_NODES * 4;          // 12.8 MB
  const size_t nodeB    = (N_NODES * 4 + 255) & ~(size_t)255;    // 200192 B
  const size_t needed   = partialB + 2 * nodeB + 1024;

  if (ws_size >= needed) {
    float* partial = (float*)ws;
    float* dinv    = (float*)(ws + partialB);
    float* w       = (float*)(ws + partialB + nodeB);
    float* vacc    = (float*)(ws + partialB + 2 * nodeB);

    dim3 sg(NSLICE, N_NODES / NQUART);   // 64 x 4 = 256 blocks
    k_scatter<false><<<sg, 1024, 0, stream>>>(dst, nullptr, nullptr, partial, E, perSlice);
    k_merge_deg<<<(N_NODES + 255) / 256, 256, 0, stream>>>(partial, dinv);
    k_scatter<true><<<sg, 1024, 0, stream>>>(src, dst, dinv, partial, E, perSlice);
    k_merge_w<<<(N_NODES + 255) / 256, 256, 0, stream>>>(partial, dinv, w, vacc);
    dim3 grid(128, 2);
    k_main<<<grid, 256, 0, stream>>>(x, Wf, bf, w, vacc);
    k_final<<<1, 256, 0, stream>>>(vacc, Wg, bg, W1, b1, W2, b2, out);
  } else {
    // fallback: device-atomic path (R1)
    int*   deg  = (int*)ws;
    float* s    = (float*)(ws + nodeB);
    float* vacc = (float*)(ws + 2 * nodeB);
    k_init<<<(N_NODES + 255) / 256, 256, 0, stream>>>(deg, s, vacc);
    k_deg_at<<<(E + 255) / 256, 256, 0, stream>>>(dst, deg, E);
    k_s_at<<<(E + 255) / 256, 256, 0, stream>>>(src, dst, deg, s, E);
    k_w_at<<<(N_NODES + 255) / 256, 256, 0, stream>>>(deg, s);
    dim3 grid(128, 2);
    k_main<<<grid, 256, 0, stream>>>(x, Wf, bf, s, vacc);
    k_final<<<1, 256, 0, stream>>>(vacc, Wg, bg, W1, b1, W2, b2, out);
  }
  (void)n_in; (void)out_size; (void)ws_size;
}